// Round 5
// baseline (36010.040 us; speedup 1.0000x reference)
//
#include <hip/hip_runtime.h>
#include <hip/hip_bf16.h>
#include <math.h>

// ===== fresh literal transcription of the MLA reference. No code reuse. =====
// shapes: x(2,2048,2048) wq(2048,3072) wkv_a(2048,576) w(512) wkv_b(512,4096) wo(2048,2048)

#define NB 2
#define NS 2048
#define ND 2048
#define NH 16
#define DNOPE 128
#define DROPE 64
#define DVAL 128
#define RANK 512
#define QW (NH*(DNOPE+DROPE))    // 3072
#define AW (RANK+DROPE)          // 576
#define BW (NH*(DNOPE+DVAL))     // 4096
#define OW (NH*DVAL)             // 2048
#define ATT_SCALE 0.07216878364870322f

// C[M,N] = A(M x K, row stride lda) @ B(K x N). Flat grid-stride, K DESCENDING.
__global__ __launch_bounds__(256) void k_gemm(const float* __restrict__ A,
                                              const float* __restrict__ B,
                                              float* __restrict__ C,
                                              int M, int N, int K, int lda) {
  const long total = (long)M * N;
  for (long i = (long)blockIdx.x * 256 + threadIdx.x; i < total; i += (long)gridDim.x * 256) {
    const int r = (int)(i / N);
    const int c = (int)(i % N);
    const float* a = A + (long)r * lda;
    float acc = 0.f;
    for (int k = K - 1; k >= 0; --k)            // descending on purpose
      acc += a[k] * B[(long)k * N + c];
    C[i] = acc;
  }
}

// RMS-norm first 512 cols of each 576-wide row, in place. fp64 reduction.
__global__ __launch_bounds__(256) void k_rms(float* __restrict__ kva,
                                             const float* __restrict__ w) {
  const int row = blockIdx.x;
  float* p = kva + (long)row * AW;
  __shared__ double sd[256];
  double ss = 0.0;
  for (int j = threadIdx.x; j < RANK; j += 256) { double v = p[j]; ss += v * v; }
  sd[threadIdx.x] = ss;
  __syncthreads();
  for (int st = 128; st > 0; st >>= 1) {
    if (threadIdx.x < st) sd[threadIdx.x] += sd[threadIdx.x + st];
    __syncthreads();
  }
  const float sc = (float)(1.0 / sqrt(sd[0] / (double)RANK + 1e-6));
  for (int j = threadIdx.x; j < RANK; j += 256) p[j] = p[j] * sc * w[j];
}

// rope k_pe: cols 512..575 of kva row, pairs (512+2i, 512+2i+1), fp64 trig.
__global__ __launch_bounds__(64) void k_ropek(float* __restrict__ kva) {
  const int row = blockIdx.x;
  const int i = threadIdx.x;
  if (i >= 32) return;
  const double invf = pow(10000.0, -(double)i / 32.0);
  const double ang = (double)row * invf;
  const float c = (float)cos(ang), s = (float)sin(ang);
  float* p = kva + (long)row * AW + RANK + 2 * i;
  const float x0 = p[0], x1 = p[1];
  p[0] = x0 * c - x1 * s;
  p[1] = x0 * s + x1 * c;
}

// rope q_pe: per head h, dims 128+2i / 128+2i+1 of that head's 192 slice.
__global__ __launch_bounds__(512) void k_ropeq(float* __restrict__ q) {
  const int row = blockIdx.x;
  const int h = threadIdx.x >> 5;
  const int i = threadIdx.x & 31;
  const double invf = pow(10000.0, -(double)i / 32.0);
  const double ang = (double)row * invf;
  const float c = (float)cos(ang), s = (float)sin(ang);
  float* p = q + (long)row * QW + h * (DNOPE + DROPE) + DNOPE + 2 * i;
  const float x0 = p[0], x1 = p[1];
  p[0] = x0 * c - x1 * s;
  p[1] = x0 * s + x1 * c;
}

// attention, one block per (query row, head). two-pass, fp64 sums, descending-t PV.
__global__ __launch_bounds__(256) void k_attn(const float* __restrict__ q,
                                              const float* __restrict__ kvb,
                                              const float* __restrict__ kva,
                                              float* __restrict__ att) {
  const int s = blockIdx.x;
  const int h = blockIdx.y;
  const int tid = threadIdx.x;
  const int nk = s + 1;
  __shared__ float qs[192];
  __shared__ float sc[NS];
  __shared__ double rd[256];

  for (int d = tid; d < 192; d += 256)
    qs[d] = q[(long)s * QW + h * (DNOPE + DROPE) + d];
  __syncthreads();

  for (int t = tid; t < nk; t += 256) {
    const float* kn = kvb + (long)t * BW + h * (DNOPE + DVAL);
    const float* kp = kva + (long)t * AW + RANK;
    float acc = 0.f;
    for (int d = DNOPE - 1; d >= 0; --d) acc += qs[d] * kn[d];
    for (int d = DROPE - 1; d >= 0; --d) acc += qs[DNOPE + d] * kp[d];
    sc[t] = acc * ATT_SCALE;
  }
  __syncthreads();

  float m = -1e30f;
  for (int t = tid; t < nk; t += 256) m = fmaxf(m, sc[t]);
  rd[tid] = (double)m;
  __syncthreads();
  for (int st = 128; st > 0; st >>= 1) {
    if (tid < st) rd[tid] = fmax(rd[tid], rd[tid + st]);
    __syncthreads();
  }
  m = (float)rd[0];
  __syncthreads();

  double ls = 0.0;
  for (int t = tid; t < nk; t += 256) {
    float pp = expf(sc[t] - m);
    sc[t] = pp;
    ls += (double)pp;
  }
  rd[tid] = ls;
  __syncthreads();
  for (int st = 128; st > 0; st >>= 1) {
    if (tid < st) rd[tid] += rd[tid + st];
    __syncthreads();
  }
  const float invl = (float)(1.0 / rd[0]);
  __syncthreads();

  if (tid < DVAL) {
    float acc = 0.f;
    for (int t = nk - 1; t >= 0; --t)
      acc += sc[t] * kvb[(long)t * BW + h * (DNOPE + DVAL) + DNOPE + tid];
    att[(long)s * OW + h * DVAL + tid] = acc * invl;
  }
}

extern "C" void kernel_launch(void* const* d_in, const int* in_sizes, int n_in,
                              void* d_out, int out_size, void* d_ws, size_t ws_size,
                              hipStream_t stream) {
  const float* x      = (const float*)d_in[0];
  const float* wq     = (const float*)d_in[1];
  const float* wkv_a  = (const float*)d_in[2];
  const float* w_norm = (const float*)d_in[3];
  const float* wkv_b  = (const float*)d_in[4];
  const float* wo     = (const float*)d_in[5];
  float* out = (float*)d_out;

  // per-batch ws: q 25.2MB | kva 4.7MB | kvb 33.6MB | att 16.8MB  (80.2MB total)
  float* q   = (float*)d_ws;
  float* kva = q + (long)NS * QW;
  float* kvb = kva + (long)NS * AW;
  float* att = kvb + (long)NS * BW;

  for (int b = 0; b < NB; ++b) {
    const float* xb = x + (long)b * NS * ND;
    float* outb = out + (long)b * NS * ND;
    k_gemm<<<dim3(2048), dim3(256), 0, stream>>>(xb, wq, q, NS, QW, ND, ND);
    k_gemm<<<dim3(2048), dim3(256), 0, stream>>>(xb, wkv_a, kva, NS, AW, ND, ND);
    k_rms<<<dim3(NS), dim3(256), 0, stream>>>(kva, w_norm);
    k_ropek<<<dim3(NS), dim3(64), 0, stream>>>(kva);
    k_ropeq<<<dim3(NS), dim3(512), 0, stream>>>(q);
    k_gemm<<<dim3(2048), dim3(256), 0, stream>>>(kva, wkv_b, kvb, NS, BW, RANK, AW);
    k_attn<<<dim3(NS, NH), dim3(256), 0, stream>>>(q, kvb, kva, att);
    k_gemm<<<dim3(2048), dim3(256), 0, stream>>>(att, wo, outb, NS, ND, OW, OW);
  }
}

// Round 6
// 7054.179 us; speedup vs baseline: 5.1048x; 5.1048x over previous
//
#include <hip/hip_runtime.h>
#include <hip/hip_bf16.h>
#include <math.h>

#define NB 2
#define NS 2048
#define ND 2048
#define NH 16
#define DNOPE 128
#define DROPE 64
#define DVAL 128
#define RANK 512
#define QW (NH*(DNOPE+DROPE))    // 3072
#define AW (RANK+DROPE)          // 576
#define AWPAD 640
#define BW (NH*(DNOPE+DVAL))     // 4096
#define OW (NH*DVAL)             // 2048
#define ATT_SCALE 0.07216878364870322f

typedef __attribute__((ext_vector_type(8))) short short8;
typedef __attribute__((ext_vector_type(4))) float f32x4;

__device__ __forceinline__ float b2f(unsigned short u) {
  unsigned x = ((unsigned)u) << 16; float f; __builtin_memcpy(&f, &x, 4); return f;
}
__device__ __forceinline__ unsigned short f2b(float f) {
  unsigned x; __builtin_memcpy(&x, &f, 4);
  unsigned r = (x + 0x7fffu + ((x >> 16) & 1u)) >> 16;
  return (unsigned short)r;
}
__device__ __forceinline__ void gload16(const void* g, void* lds) {
  __builtin_amdgcn_global_load_lds((const __attribute__((address_space(1))) void*)g,
                                   (__attribute__((address_space(3))) void*)lds, 16, 0, 0);
}

// ---------- fp32 -> bf16 flat convert (n divisible by 1024*... launch exact) ----------
__global__ __launch_bounds__(256) void k_cvt(const float* __restrict__ X,
                                             unsigned short* __restrict__ Y) {
  long i = ((long)blockIdx.x * 256 + threadIdx.x) * 4;
  float4 v = *(const float4*)(X + i);
  ushort4 o;
  o.x = f2b(v.x); o.y = f2b(v.y); o.z = f2b(v.z); o.w = f2b(v.w);
  *(ushort4*)(Y + i) = o;
}

// ---------- transpose+convert: W fp32 [K][N] -> WT bf16 [Npad][K], zero pad ----------
__global__ __launch_bounds__(256) void k_transpose(const float* __restrict__ W,
                                                   unsigned short* __restrict__ WT,
                                                   int K, int N) {
  __shared__ float t[32][33];
  const int k0 = blockIdx.x * 32, n0 = blockIdx.y * 32;
  const int tx = threadIdx.x & 31, ty = threadIdx.x >> 5;   // ty 0..7
  #pragma unroll
  for (int i = 0; i < 32; i += 8) {
    int n = n0 + tx;
    float v = (n < N) ? W[(size_t)(k0 + ty + i) * N + n] : 0.f;
    t[ty + i][tx] = v;
  }
  __syncthreads();
  #pragma unroll
  for (int i = 0; i < 32; i += 8)
    WT[(size_t)(n0 + ty + i) * K + k0 + tx] = f2b(t[tx][ty + i]);
}

// ---------- bf16 MFMA GEMM: C[M,N] = A[M,K(lda)] @ BT[N,K]^T ----------
// 256 thr, tile 128x128, BK=64, waves 2x2 of 64x64, XOR-swizzled LDS, global_load_lds.
template <typename OutT>
__global__ __launch_bounds__(256) void gemm_bf16(
    const unsigned short* __restrict__ A, const unsigned short* __restrict__ BT,
    OutT* __restrict__ C, int M, int N, int K, int lda) {
  __shared__ short8 AsV[1024];   // [row 0..127][slot 0..7] 16KB
  __shared__ short8 BsV[1024];
  const int tid = threadIdx.x;
  const int l = tid & 63, w = tid >> 6;
  const int bm = blockIdx.y * 128, bn = blockIdx.x * 128;
  const int wm = (w >> 1) * 64, wn = (w & 1) * 64;
  f32x4 acc[4][4] = {};

  // staging geometry: issue i covers LDS rows [i*32, i*32+32); thread -> row i*32 + tid/8,
  // 16B slot (tid&7), global k pre-swizzled: gk = (((tid&7)*16) ^ ((row&7)<<4)) / 2
  const int srow = tid >> 3;                       // + i*32
  const int gk   = ((((tid & 7) * 16) ^ ((srow & 7) << 4)) >> 1);
  const int sw   = l & 7;

  for (int k0 = 0; k0 < K; k0 += 64) {
    #pragma unroll
    for (int i = 0; i < 4; ++i) {
      const int row = i * 32 + srow;
      gload16(A + (size_t)(bm + row) * lda + k0 + gk, (char*)AsV + i * 4096 + w * 1024);
      gload16(BT + (size_t)(bn + row) * K   + k0 + gk, (char*)BsV + i * 4096 + w * 1024);
    }
    __syncthreads();
    #pragma unroll
    for (int kk2 = 0; kk2 < 2; ++kk2) {            // kk = kk2*32
      const int kb = kk2 * 4 + (l >> 4);           // (kk*2 + (l>>4)*16)>>4
      short8 af[4], bg[4];
      #pragma unroll
      for (int mi = 0; mi < 4; ++mi)
        af[mi] = AsV[(wm + mi * 16 + (l & 15)) * 8 + (kb ^ sw)];
      #pragma unroll
      for (int ni = 0; ni < 4; ++ni)
        bg[ni] = BsV[(wn + ni * 16 + (l & 15)) * 8 + (kb ^ sw)];
      #pragma unroll
      for (int mi = 0; mi < 4; ++mi)
        #pragma unroll
        for (int ni = 0; ni < 4; ++ni)
          acc[mi][ni] = __builtin_amdgcn_mfma_f32_16x16x32_bf16(af[mi], bg[ni], acc[mi][ni], 0, 0, 0);
    }
    __syncthreads();
  }

  const int r0 = bm + wm + (l >> 4) * 4;
  const int c0 = bn + wn + (l & 15);
  #pragma unroll
  for (int mi = 0; mi < 4; ++mi)
    #pragma unroll
    for (int ni = 0; ni < 4; ++ni) {
      const int col = c0 + ni * 16;
      if (col < N) {
        #pragma unroll
        for (int j = 0; j < 4; ++j) {
          float v = acc[mi][ni][j];
          if constexpr (__is_same(OutT, float))
            C[(size_t)(r0 + mi * 16 + j) * N + col] = v;
          else
            C[(size_t)(r0 + mi * 16 + j) * N + col] = f2b(v);
        }
      }
    }
}

// ---------- RMSNorm on bf16 kva rows (first 512 cols), in place ----------
__global__ __launch_bounds__(256) void k_rms_b(unsigned short* __restrict__ kva,
                                               const float* __restrict__ w) {
  const int row = blockIdx.x;
  unsigned short* p = kva + (long)row * AW;
  __shared__ float sd[256];
  float ss = 0.f;
  for (int j = threadIdx.x; j < RANK; j += 256) { float v = b2f(p[j]); ss += v * v; }
  sd[threadIdx.x] = ss;
  __syncthreads();
  for (int st = 128; st > 0; st >>= 1) {
    if (threadIdx.x < st) sd[threadIdx.x] += sd[threadIdx.x + st];
    __syncthreads();
  }
  const float sc = rsqrtf(sd[0] / (float)RANK + 1e-6f);
  for (int j = threadIdx.x; j < RANK; j += 256) p[j] = f2b(b2f(p[j]) * sc * w[j]);
}

// ---------- RoPE k_pe: cols 512..575 of bf16 kva ----------
__global__ __launch_bounds__(64) void k_ropek_b(unsigned short* __restrict__ kva) {
  const int row = blockIdx.x;
  const int i = threadIdx.x;
  if (i >= 32) return;
  const double invf = pow(10000.0, -(double)i / 32.0);
  const double ang = (double)row * invf;
  const float c = (float)cos(ang), s = (float)sin(ang);
  unsigned short* p = kva + (long)row * AW + RANK + 2 * i;
  const float x0 = b2f(p[0]), x1 = b2f(p[1]);
  p[0] = f2b(x0 * c - x1 * s);
  p[1] = f2b(x0 * s + x1 * c);
}

// ---------- RoPE q_pe on bf16 q ----------
__global__ __launch_bounds__(512) void k_ropeq_b(unsigned short* __restrict__ q) {
  const int row = blockIdx.x;
  const int h = threadIdx.x >> 5;
  const int i = threadIdx.x & 31;
  const double invf = pow(10000.0, -(double)i / 32.0);
  const double ang = (double)row * invf;
  const float c = (float)cos(ang), s = (float)sin(ang);
  unsigned short* p = q + (long)row * QW + h * (DNOPE + DROPE) + DNOPE + 2 * i;
  const float x0 = b2f(p[0]), x1 = b2f(p[1]);
  p[0] = f2b(x0 * c - x1 * s);
  p[1] = f2b(x0 * s + x1 * c);
}

// ---------- attention (bf16 in/out), one block per (row, head), two-pass ----------
__global__ __launch_bounds__(256) void k_attn_b(const unsigned short* __restrict__ q,
                                                const unsigned short* __restrict__ kvb,
                                                const unsigned short* __restrict__ kva,
                                                unsigned short* __restrict__ att) {
  const int s = blockIdx.x;
  const int h = blockIdx.y;
  const int tid = threadIdx.x;
  const int nk = s + 1;
  __shared__ float qs[192];
  __shared__ float sc[NS];
  __shared__ float rd[256];
  __shared__ float pv[2][DVAL];

  for (int d = tid; d < 192; d += 256)
    qs[d] = b2f(q[(long)s * QW + h * (DNOPE + DROPE) + d]);
  __syncthreads();

  for (int t = tid; t < nk; t += 256) {
    const ushort4* kn = (const ushort4*)(kvb + (long)t * BW + h * (DNOPE + DVAL));
    const ushort4* kp = (const ushort4*)(kva + (long)t * AW + RANK);
    float acc = 0.f;
    #pragma unroll 8
    for (int d4 = 0; d4 < 32; ++d4) {
      ushort4 u = kn[d4];
      acc += qs[4*d4+0] * b2f(u.x) + qs[4*d4+1] * b2f(u.y)
           + qs[4*d4+2] * b2f(u.z) + qs[4*d4+3] * b2f(u.w);
    }
    #pragma unroll 8
    for (int d4 = 0; d4 < 16; ++d4) {
      ushort4 u = kp[d4];
      acc += qs[128+4*d4+0] * b2f(u.x) + qs[128+4*d4+1] * b2f(u.y)
           + qs[128+4*d4+2] * b2f(u.z) + qs[128+4*d4+3] * b2f(u.w);
    }
    sc[t] = acc * ATT_SCALE;
  }
  __syncthreads();

  float m = -1e30f;
  for (int t = tid; t < nk; t += 256) m = fmaxf(m, sc[t]);
  rd[tid] = m;
  __syncthreads();
  for (int st = 128; st > 0; st >>= 1) {
    if (tid < st) rd[tid] = fmaxf(rd[tid], rd[tid + st]);
    __syncthreads();
  }
  m = rd[0];
  __syncthreads();

  float ls = 0.f;
  for (int t = tid; t < nk; t += 256) {
    float pp = expf(sc[t] - m);
    sc[t] = pp;
    ls += pp;
  }
  rd[tid] = ls;
  __syncthreads();
  for (int st = 128; st > 0; st >>= 1) {
    if (tid < st) rd[tid] += rd[tid + st];
    __syncthreads();
  }
  const float invl = 1.0f / rd[0];
  __syncthreads();

  {
    const int d = tid & 127, half = tid >> 7;
    float acc = 0.f;
    for (int t = half; t < nk; t += 2)
      acc += sc[t] * b2f(kvb[(long)t * BW + h * (DNOPE + DVAL) + DNOPE + d]);
    pv[half][d] = acc;
  }
  __syncthreads();
  if (tid < DVAL)
    att[(long)s * OW + h * DVAL + tid] = f2b((pv[0][tid] + pv[1][tid]) * invl);
}

extern "C" void kernel_launch(void* const* d_in, const int* in_sizes, int n_in,
                              void* d_out, int out_size, void* d_ws, size_t ws_size,
                              hipStream_t stream) {
  const float* x      = (const float*)d_in[0];
  const float* wq     = (const float*)d_in[1];
  const float* wkv_a  = (const float*)d_in[2];
  const float* w_norm = (const float*)d_in[3];
  const float* wkv_b  = (const float*)d_in[4];
  const float* wo     = (const float*)d_in[5];
  float* out = (float*)d_out;

  // ws layout (bf16/ushort elements), total ~76.3 MB
  unsigned short* wqT   = (unsigned short*)d_ws;                 // 3072 x 2048
  unsigned short* wkvaT = wqT   + (long)QW * ND;                 // 640  x 2048
  unsigned short* wkvbT = wkvaT + (long)AWPAD * ND;              // 4096 x 512
  unsigned short* woT   = wkvbT + (long)BW * RANK;               // 2048 x 2048
  unsigned short* xb    = woT   + (long)ND * OW;                 // 2048 x 2048 (per batch)
  unsigned short* q     = xb    + (long)NS * ND;                 // 2048 x 3072
  unsigned short* kva   = q     + (long)NS * QW;                 // 2048 x 576
  unsigned short* kvb   = kva   + (long)NS * AW;                 // 2048 x 4096
  unsigned short* att   = kvb   + (long)NS * BW;                 // 2048 x 2048

  // one-time weight prep
  k_transpose<<<dim3(ND / 32, QW / 32),    dim3(256), 0, stream>>>(wq,    wqT,   ND,  QW);
  k_transpose<<<dim3(ND / 32, AWPAD / 32), dim3(256), 0, stream>>>(wkv_a, wkvaT, ND,  AW);
  k_transpose<<<dim3(RANK / 32, BW / 32),  dim3(256), 0, stream>>>(wkv_b, wkvbT, RANK, BW);
  k_transpose<<<dim3(OW / 32, ND / 32),    dim3(256), 0, stream>>>(wo,    woT,   OW,  ND);

  for (int b = 0; b < NB; ++b) {
    const float* xf = x + (long)b * NS * ND;
    float* outb = out + (long)b * NS * ND;
    k_cvt<<<dim3((NS * ND) / 1024), dim3(256), 0, stream>>>(xf, xb);
    // q = x @ wq
    gemm_bf16<unsigned short><<<dim3(QW / 128, NS / 128), dim3(256), 0, stream>>>(
        xb, wqT, q, NS, QW, ND, ND);
    // kva = x @ wkv_a  (N=576 -> 5 col tiles, BT padded)
    gemm_bf16<unsigned short><<<dim3(5, NS / 128), dim3(256), 0, stream>>>(
        xb, wkvaT, kva, NS, AW, ND, ND);
    k_rms_b<<<dim3(NS), dim3(256), 0, stream>>>(kva, w_norm);
    k_ropek_b<<<dim3(NS), dim3(64), 0, stream>>>(kva);
    k_ropeq_b<<<dim3(NS), dim3(512), 0, stream>>>(q);
    // kvb = kv_n @ wkv_b  (A row stride 576, K=512)
    gemm_bf16<unsigned short><<<dim3(BW / 128, NS / 128), dim3(256), 0, stream>>>(
        kva, wkvbT, kvb, NS, BW, RANK, AW);
    k_attn_b<<<dim3(NS, NH), dim3(256), 0, stream>>>(q, kvb, kva, att);
    // out = att @ wo (fp32 store)
    gemm_bf16<float><<<dim3(ND / 128, NS / 128), dim3(256), 0, stream>>>(
        att, woT, outb, NS, ND, OW, OW);
  }
}

// Round 7
// 577.156 us; speedup vs baseline: 62.3923x; 12.2223x over previous
//
#include <hip/hip_runtime.h>
#include <hip/hip_bf16.h>
#include <math.h>

#define NB 2
#define NS 2048
#define ND 2048
#define NH 16
#define DNOPE 128
#define DROPE 64
#define DVAL 128
#define RANK 512
#define QW (NH*(DNOPE+DROPE))    // 3072
#define AW (RANK+DROPE)          // 576
#define AWPAD 640
#define BW (NH*(DNOPE+DVAL))     // 4096
#define OW (NH*DVAL)             // 2048
#define ATT_SCALE 0.07216878364870322f

typedef __attribute__((ext_vector_type(8))) short short8;
typedef __attribute__((ext_vector_type(4))) float f32x4;

__device__ __forceinline__ float b2f(unsigned short u) {
  unsigned x = ((unsigned)u) << 16; float f; __builtin_memcpy(&f, &x, 4); return f;
}
__device__ __forceinline__ unsigned short f2b(float f) {
  unsigned x; __builtin_memcpy(&x, &f, 4);
  unsigned r = (x + 0x7fffu + ((x >> 16) & 1u)) >> 16;
  return (unsigned short)r;
}
__device__ __forceinline__ void gload16(const void* g, void* lds) {
  __builtin_amdgcn_global_load_lds((const __attribute__((address_space(1))) void*)g,
                                   (__attribute__((address_space(3))) void*)lds, 16, 0, 0);
}

// ---------- fp32 -> bf16 flat convert ----------
__global__ __launch_bounds__(256) void k_cvt(const float* __restrict__ X,
                                             unsigned short* __restrict__ Y) {
  long i = ((long)blockIdx.x * 256 + threadIdx.x) * 4;
  float4 v = *(const float4*)(X + i);
  ushort4 o;
  o.x = f2b(v.x); o.y = f2b(v.y); o.z = f2b(v.z); o.w = f2b(v.w);
  *(ushort4*)(Y + i) = o;
}

// ---------- transpose+convert: W fp32 [K][N] -> WT bf16 [Npad][K], zero pad ----------
__global__ __launch_bounds__(256) void k_transpose(const float* __restrict__ W,
                                                   unsigned short* __restrict__ WT,
                                                   int K, int N) {
  __shared__ float t[32][33];
  const int k0 = blockIdx.x * 32, n0 = blockIdx.y * 32;
  const int tx = threadIdx.x & 31, ty = threadIdx.x >> 5;
  #pragma unroll
  for (int i = 0; i < 32; i += 8) {
    int n = n0 + tx;
    float v = (n < N) ? W[(size_t)(k0 + ty + i) * N + n] : 0.f;
    t[ty + i][tx] = v;
  }
  __syncthreads();
  #pragma unroll
  for (int i = 0; i < 32; i += 8)
    WT[(size_t)(n0 + ty + i) * K + k0 + tx] = f2b(t[tx][ty + i]);
}

// ---------- bf16 MFMA GEMM (validated round 6) ----------
template <typename OutT>
__global__ __launch_bounds__(256) void gemm_bf16(
    const unsigned short* __restrict__ A, const unsigned short* __restrict__ BT,
    OutT* __restrict__ C, int M, int N, int K, int lda) {
  __shared__ short8 AsV[1024];
  __shared__ short8 BsV[1024];
  const int tid = threadIdx.x;
  const int l = tid & 63, w = tid >> 6;
  const int bm = blockIdx.y * 128, bn = blockIdx.x * 128;
  const int wm = (w >> 1) * 64, wn = (w & 1) * 64;
  f32x4 acc[4][4] = {};

  const int srow = tid >> 3;
  const int gk   = ((((tid & 7) * 16) ^ ((srow & 7) << 4)) >> 1);
  const int sw   = l & 7;

  for (int k0 = 0; k0 < K; k0 += 64) {
    #pragma unroll
    for (int i = 0; i < 4; ++i) {
      const int row = i * 32 + srow;
      gload16(A + (size_t)(bm + row) * lda + k0 + gk, (char*)AsV + i * 4096 + w * 1024);
      gload16(BT + (size_t)(bn + row) * K   + k0 + gk, (char*)BsV + i * 4096 + w * 1024);
    }
    __syncthreads();
    #pragma unroll
    for (int kk2 = 0; kk2 < 2; ++kk2) {
      const int kb = kk2 * 4 + (l >> 4);
      short8 af[4], bg[4];
      #pragma unroll
      for (int mi = 0; mi < 4; ++mi)
        af[mi] = AsV[(wm + mi * 16 + (l & 15)) * 8 + (kb ^ sw)];
      #pragma unroll
      for (int ni = 0; ni < 4; ++ni)
        bg[ni] = BsV[(wn + ni * 16 + (l & 15)) * 8 + (kb ^ sw)];
      #pragma unroll
      for (int mi = 0; mi < 4; ++mi)
        #pragma unroll
        for (int ni = 0; ni < 4; ++ni)
          acc[mi][ni] = __builtin_amdgcn_mfma_f32_16x16x32_bf16(af[mi], bg[ni], acc[mi][ni], 0, 0, 0);
    }
    __syncthreads();
  }

  const int r0 = bm + wm + (l >> 4) * 4;
  const int c0 = bn + wn + (l & 15);
  #pragma unroll
  for (int mi = 0; mi < 4; ++mi)
    #pragma unroll
    for (int ni = 0; ni < 4; ++ni) {
      const int col = c0 + ni * 16;
      if (col < N) {
        #pragma unroll
        for (int j = 0; j < 4; ++j) {
          float v = acc[mi][ni][j];
          if constexpr (__is_same(OutT, float))
            C[(size_t)(r0 + mi * 16 + j) * N + col] = v;
          else
            C[(size_t)(r0 + mi * 16 + j) * N + col] = f2b(v);
        }
      }
    }
}

// ---------- RMSNorm on bf16 kva rows ----------
__global__ __launch_bounds__(256) void k_rms_b(unsigned short* __restrict__ kva,
                                               const float* __restrict__ w) {
  const int row = blockIdx.x;
  unsigned short* p = kva + (long)row * AW;
  __shared__ float sd[256];
  float ss = 0.f;
  for (int j = threadIdx.x; j < RANK; j += 256) { float v = b2f(p[j]); ss += v * v; }
  sd[threadIdx.x] = ss;
  __syncthreads();
  for (int st = 128; st > 0; st >>= 1) {
    if (threadIdx.x < st) sd[threadIdx.x] += sd[threadIdx.x + st];
    __syncthreads();
  }
  const float sc = rsqrtf(sd[0] / (float)RANK + 1e-6f);
  for (int j = threadIdx.x; j < RANK; j += 256) p[j] = f2b(b2f(p[j]) * sc * w[j]);
}

// ---------- RoPE k_pe ----------
__global__ __launch_bounds__(64) void k_ropek_b(unsigned short* __restrict__ kva) {
  const int row = blockIdx.x;
  const int i = threadIdx.x;
  if (i >= 32) return;
  const double invf = pow(10000.0, -(double)i / 32.0);
  const double ang = (double)row * invf;
  const float c = (float)cos(ang), s = (float)sin(ang);
  unsigned short* p = kva + (long)row * AW + RANK + 2 * i;
  const float x0 = b2f(p[0]), x1 = b2f(p[1]);
  p[0] = f2b(x0 * c - x1 * s);
  p[1] = f2b(x0 * s + x1 * c);
}

// ---------- RoPE q_pe ----------
__global__ __launch_bounds__(512) void k_ropeq_b(unsigned short* __restrict__ q) {
  const int row = blockIdx.x;
  const int h = threadIdx.x >> 5;
  const int i = threadIdx.x & 31;
  const double invf = pow(10000.0, -(double)i / 32.0);
  const double ang = (double)row * invf;
  const float c = (float)cos(ang), s = (float)sin(ang);
  unsigned short* p = q + (long)row * QW + h * (DNOPE + DROPE) + DNOPE + 2 * i;
  const float x0 = b2f(p[0]), x1 = b2f(p[1]);
  p[0] = f2b(x0 * c - x1 * s);
  p[1] = f2b(x0 * s + x1 * c);
}

// ---------- MFMA flash attention ----------
// grid (NS/64, NH), 256 thr = 4 waves, wave owns 16 q-rows. K tiles of 64 keys.
#define QBLK 64
#define KBLK 64
#define KSL 24               // 16B slots per K row (192 bf16)
#define VTS 72               // VT row stride (elems)
#define PLS 72               // P row stride (elems)
__global__ __launch_bounds__(256) void k_attn_mfma(
    const unsigned short* __restrict__ q,
    const unsigned short* __restrict__ kvb,
    const unsigned short* __restrict__ kva,
    unsigned short* __restrict__ att) {
  __shared__ short8 Ks[KBLK * KSL];                       // 24 KB, slot-swizzled
  __shared__ __align__(16) unsigned short VT[DVAL * VTS]; // 18 KB, V transposed
  __shared__ __align__(16) unsigned short Pl[QBLK * PLS]; // 9 KB
  const int tid = threadIdx.x;
  const int l = tid & 63, w = tid >> 6;
  const int g = l >> 4, r16 = l & 15;
  const int qt = blockIdx.x, h = blockIdx.y;
  const int qrow0 = qt * QBLK + w * 16;

  // Q A-frags: 16 rows x 192, resident in registers
  short8 aq[6];
  {
    const unsigned short* qp = q + (size_t)(qrow0 + r16) * QW + h * 192 + g * 8;
    #pragma unroll
    for (int f = 0; f < 6; ++f) aq[f] = *(const short8*)(qp + f * 32);
  }

  f32x4 o[8] = {};
  float m_j[4], l_j[4];
  #pragma unroll
  for (int j = 0; j < 4; ++j) { m_j[j] = -1e30f; l_j[j] = 0.f; }

  for (int kt = 0; kt <= qt; ++kt) {
    const int kbase = kt * KBLK;
    // stage K (64x192) swizzled: phys slot p holds logical s = (p&~7)|((p&7)^(row&7))
    #pragma unroll
    for (int i = 0; i < 6; ++i) {
      const int chunk = i * 256 + tid;
      const int row = chunk / KSL, p = chunk % KSL;
      const int s = (p & ~7) | ((p & 7) ^ (row & 7));
      const int d0 = s * 8;
      const unsigned short* src =
          (d0 < DNOPE) ? kvb + (size_t)(kbase + row) * BW + h * 256 + d0
                       : kva + (size_t)(kbase + row) * AW + RANK + (d0 - DNOPE);
      gload16(src, (char*)Ks + (size_t)(i * 256 + (tid & ~63)) * 16);
    }
    // stage V^T (VT[d][t])
    {
      const int t = tid >> 2;
      const int dq = (tid & 3) * 8;
      #pragma unroll
      for (int pass = 0; pass < 4; ++pass) {
        const int d0 = dq + pass * 32;
        short8 v = *(const short8*)(kvb + (size_t)(kbase + t) * BW + h * 256 + DNOPE + d0);
        #pragma unroll
        for (int jj = 0; jj < 8; ++jj)
          VT[(d0 + jj) * VTS + t] = (unsigned short)v[jj];
      }
    }
    __syncthreads();

    // S = Q K^T : per-wave 16x64 in 4 f32x4
    f32x4 sa[4] = {};
    #pragma unroll
    for (int f = 0; f < 6; ++f) {
      #pragma unroll
      for (int n = 0; n < 4; ++n) {
        const int row = n * 16 + r16;
        const int s = f * 4 + g;
        const int phys = (s & ~7) | ((s & 7) ^ (row & 7));
        short8 bg = Ks[row * KSL + phys];
        sa[n] = __builtin_amdgcn_mfma_f32_16x16x32_bf16(aq[f], bg, sa[n], 0, 0, 0);
      }
    }

    // online softmax (rows = g*4+j, cols spread over r16 x 4 ntiles)
    const bool diag = (kt == qt);
    float pj[4][4];
    #pragma unroll
    for (int n = 0; n < 4; ++n) {
      const int key = kbase + n * 16 + r16;
      #pragma unroll
      for (int j = 0; j < 4; ++j) {
        float v = sa[n][j] * ATT_SCALE;
        if (diag && key > (qrow0 + g * 4 + j)) v = -1e30f;
        pj[n][j] = v;
      }
    }
    #pragma unroll
    for (int j = 0; j < 4; ++j) {
      float mx = fmaxf(fmaxf(pj[0][j], pj[1][j]), fmaxf(pj[2][j], pj[3][j]));
      #pragma unroll
      for (int o2 = 1; o2 < 16; o2 <<= 1) mx = fmaxf(mx, __shfl_xor(mx, o2, 64));
      const float mn = fmaxf(m_j[j], mx);
      const float c = __expf(m_j[j] - mn);
      float rs = 0.f;
      #pragma unroll
      for (int n = 0; n < 4; ++n) {
        float p = __expf(pj[n][j] - mn);
        pj[n][j] = p;
        rs += p;
      }
      #pragma unroll
      for (int o2 = 1; o2 < 16; o2 <<= 1) rs += __shfl_xor(rs, o2, 64);
      l_j[j] = l_j[j] * c + rs;
      m_j[j] = mn;
      #pragma unroll
      for (int n8 = 0; n8 < 8; ++n8) o[n8][j] *= c;
      const int prow = w * 16 + g * 4 + j;
      #pragma unroll
      for (int n = 0; n < 4; ++n)
        Pl[prow * PLS + n * 16 + r16] = f2b(pj[n][j]);
    }

    // O += P V (own wave's P; VT shared)
    #pragma unroll
    for (int kk = 0; kk < 2; ++kk) {
      short8 pa = *(const short8*)&Pl[(w * 16 + r16) * PLS + kk * 32 + g * 8];
      #pragma unroll
      for (int n8 = 0; n8 < 8; ++n8) {
        short8 vb = *(const short8*)&VT[(n8 * 16 + r16) * VTS + kk * 32 + g * 8];
        o[n8] = __builtin_amdgcn_mfma_f32_16x16x32_bf16(pa, vb, o[n8], 0, 0, 0);
      }
    }
    __syncthreads();
  }

  #pragma unroll
  for (int j = 0; j < 4; ++j) {
    const float inv = 1.0f / l_j[j];
    const size_t rowoff = (size_t)(qrow0 + g * 4 + j) * OW + h * DVAL;
    #pragma unroll
    for (int n8 = 0; n8 < 8; ++n8)
      att[rowoff + n8 * 16 + r16] = f2b(o[n8][j] * inv);
  }
}

extern "C" void kernel_launch(void* const* d_in, const int* in_sizes, int n_in,
                              void* d_out, int out_size, void* d_ws, size_t ws_size,
                              hipStream_t stream) {
  const float* x      = (const float*)d_in[0];
  const float* wq     = (const float*)d_in[1];
  const float* wkv_a  = (const float*)d_in[2];
  const float* w_norm = (const float*)d_in[3];
  const float* wkv_b  = (const float*)d_in[4];
  const float* wo     = (const float*)d_in[5];
  float* out = (float*)d_out;

  unsigned short* wqT   = (unsigned short*)d_ws;
  unsigned short* wkvaT = wqT   + (long)QW * ND;
  unsigned short* wkvbT = wkvaT + (long)AWPAD * ND;
  unsigned short* woT   = wkvbT + (long)BW * RANK;
  unsigned short* xb    = woT   + (long)ND * OW;
  unsigned short* q     = xb    + (long)NS * ND;
  unsigned short* kva   = q     + (long)NS * QW;
  unsigned short* kvb   = kva   + (long)NS * AW;
  unsigned short* att   = kvb   + (long)NS * BW;

  k_transpose<<<dim3(ND / 32, QW / 32),    dim3(256), 0, stream>>>(wq,    wqT,   ND,  QW);
  k_transpose<<<dim3(ND / 32, AWPAD / 32), dim3(256), 0, stream>>>(wkv_a, wkvaT, ND,  AW);
  k_transpose<<<dim3(RANK / 32, BW / 32),  dim3(256), 0, stream>>>(wkv_b, wkvbT, RANK, BW);
  k_transpose<<<dim3(OW / 32, ND / 32),    dim3(256), 0, stream>>>(wo,    woT,   OW,  ND);

  for (int b = 0; b < NB; ++b) {
    const float* xf = x + (long)b * NS * ND;
    float* outb = out + (long)b * NS * ND;
    k_cvt<<<dim3((NS * ND) / 1024), dim3(256), 0, stream>>>(xf, xb);
    gemm_bf16<unsigned short><<<dim3(QW / 128, NS / 128), dim3(256), 0, stream>>>(
        xb, wqT, q, NS, QW, ND, ND);
    gemm_bf16<unsigned short><<<dim3(5, NS / 128), dim3(256), 0, stream>>>(
        xb, wkvaT, kva, NS, AW, ND, ND);
    k_rms_b<<<dim3(NS), dim3(256), 0, stream>>>(kva, w_norm);
    k_ropek_b<<<dim3(NS), dim3(64), 0, stream>>>(kva);
    k_ropeq_b<<<dim3(NS), dim3(512), 0, stream>>>(q);
    gemm_bf16<unsigned short><<<dim3(BW / 128, NS / 128), dim3(256), 0, stream>>>(
        kva, wkvbT, kvb, NS, BW, RANK, AW);
    k_attn_mfma<<<dim3(NS / QBLK, NH), dim3(256), 0, stream>>>(q, kvb, kva, att);
    gemm_bf16<float><<<dim3(ND / 128, NS / 128), dim3(256), 0, stream>>>(
        att, woT, outb, NS, ND, OW, OW);
  }
}

// Round 9
// 560.753 us; speedup vs baseline: 64.2172x; 1.0293x over previous
//
#include <hip/hip_runtime.h>
#include <hip/hip_bf16.h>
#include <math.h>

#define NB 2
#define NS 2048
#define ND 2048
#define NH 16
#define DNOPE 128
#define DROPE 64
#define DVAL 128
#define RANK 512
#define QW (NH*(DNOPE+DROPE))    // 3072
#define AW (RANK+DROPE)          // 576
#define AWPAD 640
#define BW (NH*(DNOPE+DVAL))     // 4096
#define OW (NH*DVAL)             // 2048
#define ATT_SCALE 0.07216878364870322f

typedef __attribute__((ext_vector_type(8))) short short8;
typedef __attribute__((ext_vector_type(4))) float f32x4;

__device__ __forceinline__ float b2f(unsigned short u) {
  unsigned x = ((unsigned)u) << 16; float f; __builtin_memcpy(&f, &x, 4); return f;
}
__device__ __forceinline__ unsigned short f2b(float f) {
  unsigned x; __builtin_memcpy(&x, &f, 4);
  unsigned r = (x + 0x7fffu + ((x >> 16) & 1u)) >> 16;
  return (unsigned short)r;
}
__device__ __forceinline__ void gload16(const void* g, void* lds) {
  __builtin_amdgcn_global_load_lds((const __attribute__((address_space(1))) void*)g,
                                   (__attribute__((address_space(3))) void*)lds, 16, 0, 0);
}

// ---------- fp32 -> bf16 flat convert ----------
__global__ __launch_bounds__(256) void k_cvt(const float* __restrict__ X,
                                             unsigned short* __restrict__ Y) {
  long i = ((long)blockIdx.x * 256 + threadIdx.x) * 4;
  float4 v = *(const float4*)(X + i);
  ushort4 o;
  o.x = f2b(v.x); o.y = f2b(v.y); o.z = f2b(v.z); o.w = f2b(v.w);
  *(ushort4*)(Y + i) = o;
}

// ---------- transpose+convert: W fp32 [K][N] -> WT bf16 [Npad][K], zero pad ----------
__global__ __launch_bounds__(256) void k_transpose(const float* __restrict__ W,
                                                   unsigned short* __restrict__ WT,
                                                   int K, int N) {
  __shared__ float t[32][33];
  const int k0 = blockIdx.x * 32, n0 = blockIdx.y * 32;
  const int tx = threadIdx.x & 31, ty = threadIdx.x >> 5;
  #pragma unroll
  for (int i = 0; i < 32; i += 8) {
    int n = n0 + tx;
    float v = (n < N) ? W[(size_t)(k0 + ty + i) * N + n] : 0.f;
    t[ty + i][tx] = v;
  }
  __syncthreads();
  #pragma unroll
  for (int i = 0; i < 32; i += 8)
    WT[(size_t)(n0 + ty + i) * K + k0 + tx] = f2b(t[tx][ty + i]);
}

// ---------- bf16 MFMA GEMM (validated round 6) ----------
template <typename OutT>
__global__ __launch_bounds__(256) void gemm_bf16(
    const unsigned short* __restrict__ A, const unsigned short* __restrict__ BT,
    OutT* __restrict__ C, int M, int N, int K, int lda) {
  __shared__ short8 AsV[1024];
  __shared__ short8 BsV[1024];
  const int tid = threadIdx.x;
  const int l = tid & 63, w = tid >> 6;
  const int bm = blockIdx.y * 128, bn = blockIdx.x * 128;
  const int wm = (w >> 1) * 64, wn = (w & 1) * 64;
  f32x4 acc[4][4] = {};

  const int srow = tid >> 3;
  const int gk   = ((((tid & 7) * 16) ^ ((srow & 7) << 4)) >> 1);
  const int sw   = l & 7;

  for (int k0 = 0; k0 < K; k0 += 64) {
    #pragma unroll
    for (int i = 0; i < 4; ++i) {
      const int row = i * 32 + srow;
      gload16(A + (size_t)(bm + row) * lda + k0 + gk, (char*)AsV + i * 4096 + w * 1024);
      gload16(BT + (size_t)(bn + row) * K   + k0 + gk, (char*)BsV + i * 4096 + w * 1024);
    }
    __syncthreads();
    #pragma unroll
    for (int kk2 = 0; kk2 < 2; ++kk2) {
      const int kb = kk2 * 4 + (l >> 4);
      short8 af[4], bg[4];
      #pragma unroll
      for (int mi = 0; mi < 4; ++mi)
        af[mi] = AsV[(wm + mi * 16 + (l & 15)) * 8 + (kb ^ sw)];
      #pragma unroll
      for (int ni = 0; ni < 4; ++ni)
        bg[ni] = BsV[(wn + ni * 16 + (l & 15)) * 8 + (kb ^ sw)];
      #pragma unroll
      for (int mi = 0; mi < 4; ++mi)
        #pragma unroll
        for (int ni = 0; ni < 4; ++ni)
          acc[mi][ni] = __builtin_amdgcn_mfma_f32_16x16x32_bf16(af[mi], bg[ni], acc[mi][ni], 0, 0, 0);
    }
    __syncthreads();
  }

  const int r0 = bm + wm + (l >> 4) * 4;
  const int c0 = bn + wn + (l & 15);
  #pragma unroll
  for (int mi = 0; mi < 4; ++mi)
    #pragma unroll
    for (int ni = 0; ni < 4; ++ni) {
      const int col = c0 + ni * 16;
      if (col < N) {
        #pragma unroll
        for (int j = 0; j < 4; ++j) {
          float v = acc[mi][ni][j];
          if constexpr (__is_same(OutT, float))
            C[(size_t)(r0 + mi * 16 + j) * N + col] = v;
          else
            C[(size_t)(r0 + mi * 16 + j) * N + col] = f2b(v);
        }
      }
    }
}

// ---------- RMSNorm on bf16 kva rows ----------
__global__ __launch_bounds__(256) void k_rms_b(unsigned short* __restrict__ kva,
                                               const float* __restrict__ w) {
  const int row = blockIdx.x;
  unsigned short* p = kva + (long)row * AW;
  __shared__ float sd[256];
  float ss = 0.f;
  for (int j = threadIdx.x; j < RANK; j += 256) { float v = b2f(p[j]); ss += v * v; }
  sd[threadIdx.x] = ss;
  __syncthreads();
  for (int st = 128; st > 0; st >>= 1) {
    if (threadIdx.x < st) sd[threadIdx.x] += sd[threadIdx.x + st];
    __syncthreads();
  }
  const float sc = rsqrtf(sd[0] / (float)RANK + 1e-6f);
  for (int j = threadIdx.x; j < RANK; j += 256) p[j] = f2b(b2f(p[j]) * sc * w[j]);
}

// ---------- RoPE k_pe ----------
__global__ __launch_bounds__(64) void k_ropek_b(unsigned short* __restrict__ kva) {
  const int row = blockIdx.x;
  const int i = threadIdx.x;
  if (i >= 32) return;
  const double invf = pow(10000.0, -(double)i / 32.0);
  const double ang = (double)row * invf;
  const float c = (float)cos(ang), s = (float)sin(ang);
  unsigned short* p = kva + (long)row * AW + RANK + 2 * i;
  const float x0 = b2f(p[0]), x1 = b2f(p[1]);
  p[0] = f2b(x0 * c - x1 * s);
  p[1] = f2b(x0 * s + x1 * c);
}

// ---------- RoPE q_pe ----------
__global__ __launch_bounds__(512) void k_ropeq_b(unsigned short* __restrict__ q) {
  const int row = blockIdx.x;
  const int h = threadIdx.x >> 5;
  const int i = threadIdx.x & 31;
  const double invf = pow(10000.0, -(double)i / 32.0);
  const double ang = (double)row * invf;
  const float c = (float)cos(ang), s = (float)sin(ang);
  unsigned short* p = q + (long)row * QW + h * (DNOPE + DROPE) + DNOPE + 2 * i;
  const float x0 = b2f(p[0]), x1 = b2f(p[1]);
  p[0] = f2b(x0 * c - x1 * s);
  p[1] = f2b(x0 * s + x1 * c);
}

// ---------- MFMA flash attention (round-7 structure + pairing + setprio + write-swizzle) ----------
// grid (32, 16), 256 thr = 4 waves, wave owns 16 q-rows, K tiles of 64 keys.
#define QBLK 64
#define KBLK 64
#define KSL 24               // 16B slots per K row (192 bf16)
#define VTS 72               // VT row stride (elems)
#define PLS 72               // P row stride (elems)
__global__ __launch_bounds__(256) void k_attn_mfma(
    const unsigned short* __restrict__ q,
    const unsigned short* __restrict__ kvb,
    const unsigned short* __restrict__ kva,
    unsigned short* __restrict__ att) {
  __shared__ short8 Ks[KBLK * KSL];                       // 24 KB, slot-swizzled
  __shared__ __align__(16) unsigned short VT[DVAL * VTS]; // 18 KB, V transposed
  __shared__ __align__(16) unsigned short Pl[QBLK * PLS]; // 9 KB
  const int tid = threadIdx.x;
  const int l = tid & 63, w = tid >> 6;
  const int g = l >> 4, r16 = l & 15;
  const int h = blockIdx.y;
  // causal pairing: blocks (bx,h) and (bx,h+8) are 256 apart -> same CU; work sums to 33 tiles
  const int qt = (h < 8) ? blockIdx.x : (NS / QBLK - 1) - blockIdx.x;
  const int qrow0 = qt * QBLK + w * 16;

  // Q A-frags: 16 rows x 192, resident in registers
  short8 aq[6];
  {
    const unsigned short* qp = q + (size_t)(qrow0 + r16) * QW + h * 192 + g * 8;
    #pragma unroll
    for (int f = 0; f < 6; ++f) aq[f] = *(const short8*)(qp + f * 32);
  }

  f32x4 o[8] = {};
  float m_j[4], l_j[4];
  #pragma unroll
  for (int j = 0; j < 4; ++j) { m_j[j] = -1e30f; l_j[j] = 0.f; }

  for (int kt = 0; kt <= qt; ++kt) {
    const int kbase = kt * KBLK;
    // stage K (64x192) swizzled: phys slot p holds logical s = (p&~7)|((p&7)^(row&7))
    #pragma unroll
    for (int i = 0; i < 6; ++i) {
      const int chunk = i * 256 + tid;
      const int row = chunk / KSL, p = chunk % KSL;
      const int s = (p & ~7) | ((p & 7) ^ (row & 7));
      const int d0 = s * 8;
      const unsigned short* src =
          (d0 < DNOPE) ? kvb + (size_t)(kbase + row) * BW + h * 256 + d0
                       : kva + (size_t)(kbase + row) * AW + RANK + (d0 - DNOPE);
      gload16(src, (char*)Ks + (size_t)(i * 256 + (tid & ~63)) * 16);
    }
    // stage V^T (VT[d][t]); write-order rotated so concurrent stores spread banks:
    // bank = 4*((jj+2q)&7) + (t>>1) mod 32 -> exact 2-way (free), was 16-way.
    {
      const int t = tid >> 2;
      const int qd = tid & 3;
      const int dq = qd * 8;
      #pragma unroll
      for (int pass = 0; pass < 4; ++pass) {
        const int d0 = dq + pass * 32;
        short8 v = *(const short8*)(kvb + (size_t)(kbase + t) * BW + h * 256 + DNOPE + d0);
        #pragma unroll
        for (int jj = 0; jj < 8; ++jj) {
          const int jr = (jj + 2 * qd) & 7;
          VT[(d0 + jr) * VTS + t] = (unsigned short)v[jr];
        }
      }
    }
    __syncthreads();

    // S = Q K^T : per-wave 16x64 in 4 f32x4
    f32x4 sa[4] = {};
    __builtin_amdgcn_s_setprio(1);
    #pragma unroll
    for (int f = 0; f < 6; ++f) {
      #pragma unroll
      for (int n = 0; n < 4; ++n) {
        const int row = n * 16 + r16;
        const int s = f * 4 + g;
        const int phys = (s & ~7) | ((s & 7) ^ (row & 7));
        short8 bg = Ks[row * KSL + phys];
        sa[n] = __builtin_amdgcn_mfma_f32_16x16x32_bf16(aq[f], bg, sa[n], 0, 0, 0);
      }
    }
    __builtin_amdgcn_s_setprio(0);

    // online softmax (rows = g*4+j, cols spread over r16 x 4 ntiles)
    const bool diag = (kt == qt);
    float pj[4][4];
    #pragma unroll
    for (int n = 0; n < 4; ++n) {
      const int key = kbase + n * 16 + r16;
      #pragma unroll
      for (int j = 0; j < 4; ++j) {
        float v = sa[n][j] * ATT_SCALE;
        if (diag && key > (qrow0 + g * 4 + j)) v = -1e30f;
        pj[n][j] = v;
      }
    }
    #pragma unroll
    for (int j = 0; j < 4; ++j) {
      float mx = fmaxf(fmaxf(pj[0][j], pj[1][j]), fmaxf(pj[2][j], pj[3][j]));
      #pragma unroll
      for (int o2 = 1; o2 < 16; o2 <<= 1) mx = fmaxf(mx, __shfl_xor(mx, o2, 64));
      const float mn = fmaxf(m_j[j], mx);
      const float c = __expf(m_j[j] - mn);
      float rs = 0.f;
      #pragma unroll
      for (int n = 0; n < 4; ++n) {
        float p = __expf(pj[n][j] - mn);
        pj[n][j] = p;
        rs += p;
      }
      #pragma unroll
      for (int o2 = 1; o2 < 16; o2 <<= 1) rs += __shfl_xor(rs, o2, 64);
      l_j[j] = l_j[j] * c + rs;
      m_j[j] = mn;
      #pragma unroll
      for (int n8 = 0; n8 < 8; ++n8) o[n8][j] *= c;
      const int prow = w * 16 + g * 4 + j;
      #pragma unroll
      for (int n = 0; n < 4; ++n)
        Pl[prow * PLS + n * 16 + r16] = f2b(pj[n][j]);
    }

    // O += P V (own wave's P; VT shared)
    #pragma unroll
    for (int kk = 0; kk < 2; ++kk) {
      short8 pa = *(const short8*)&Pl[(w * 16 + r16) * PLS + kk * 32 + g * 8];
      __builtin_amdgcn_s_setprio(1);
      #pragma unroll
      for (int n8 = 0; n8 < 8; ++n8) {
        short8 vb = *(const short8*)&VT[(n8 * 16 + r16) * VTS + kk * 32 + g * 8];
        o[n8] = __builtin_amdgcn_mfma_f32_16x16x32_bf16(pa, vb, o[n8], 0, 0, 0);
      }
      __builtin_amdgcn_s_setprio(0);
    }
    __syncthreads();
  }

  #pragma unroll
  for (int j = 0; j < 4; ++j) {
    const float inv = 1.0f / l_j[j];
    const size_t rowoff = (size_t)(qrow0 + g * 4 + j) * OW + h * DVAL;
    #pragma unroll
    for (int n8 = 0; n8 < 8; ++n8)
      att[rowoff + n8 * 16 + r16] = f2b(o[n8][j] * inv);
  }
}

extern "C" void kernel_launch(void* const* d_in, const int* in_sizes, int n_in,
                              void* d_out, int out_size, void* d_ws, size_t ws_size,
                              hipStream_t stream) {
  const float* x      = (const float*)d_in[0];
  const float* wq     = (const float*)d_in[1];
  const float* wkv_a  = (const float*)d_in[2];
  const float* w_norm = (const float*)d_in[3];
  const float* wkv_b  = (const float*)d_in[4];
  const float* wo     = (const float*)d_in[5];
  float* out = (float*)d_out;

  unsigned short* wqT   = (unsigned short*)d_ws;
  unsigned short* wkvaT = wqT   + (long)QW * ND;
  unsigned short* wkvbT = wkvaT + (long)AWPAD * ND;
  unsigned short* woT   = wkvbT + (long)BW * RANK;
  unsigned short* xb    = woT   + (long)ND * OW;
  unsigned short* q     = xb    + (long)NS * ND;
  unsigned short* kva   = q     + (long)NS * QW;
  unsigned short* kvb   = kva   + (long)NS * AW;
  unsigned short* att   = kvb   + (long)NS * BW;

  k_transpose<<<dim3(ND / 32, QW / 32),    dim3(256), 0, stream>>>(wq,    wqT,   ND,  QW);
  k_transpose<<<dim3(ND / 32, AWPAD / 32), dim3(256), 0, stream>>>(wkv_a, wkvaT, ND,  AW);
  k_transpose<<<dim3(RANK / 32, BW / 32),  dim3(256), 0, stream>>>(wkv_b, wkvbT, RANK, BW);
  k_transpose<<<dim3(OW / 32, ND / 32),    dim3(256), 0, stream>>>(wo,    woT,   OW,  ND);

  for (int b = 0; b < NB; ++b) {
    const float* xf = x + (long)b * NS * ND;
    float* outb = out + (long)b * NS * ND;
    k_cvt<<<dim3((NS * ND) / 1024), dim3(256), 0, stream>>>(xf, xb);
    gemm_bf16<unsigned short><<<dim3(QW / 128, NS / 128), dim3(256), 0, stream>>>(
        xb, wqT, q, NS, QW, ND, ND);
    gemm_bf16<unsigned short><<<dim3(5, NS / 128), dim3(256), 0, stream>>>(
        xb, wkvaT, kva, NS, AW, ND, ND);
    k_rms_b<<<dim3(NS), dim3(256), 0, stream>>>(kva, w_norm);
    k_ropek_b<<<dim3(NS), dim3(64), 0, stream>>>(kva);
    k_ropeq_b<<<dim3(NS), dim3(512), 0, stream>>>(q);
    gemm_bf16<unsigned short><<<dim3(BW / 128, NS / 128), dim3(256), 0, stream>>>(
        kva, wkvbT, kvb, NS, BW, RANK, AW);
    k_attn_mfma<<<dim3(NS / QBLK, NH), dim3(256), 0, stream>>>(q, kvb, kva, att);
    gemm_bf16<float><<<dim3(ND / 128, NS / 128), dim3(256), 0, stream>>>(
        att, woT, outb, NS, ND, OW, OW);
  }
}